// Round 1
// baseline (320.690 us; speedup 1.0000x reference)
//
#include <hip/hip_runtime.h>
#include <hip/hip_fp16.h>

// SpMM: out[r,:] = sum_{k: rows[k]==r} values[k] * weight[cols[k],:]  + bias
// Strategy: counting-sort nnz by row into (col,val) pairs; convert weight to
// fp16 in ws (halves gather bytes; table is 51.2 MB -> L3-resident).
// Accum: FOUR waves per output row (each takes 1/4 of the row's nnz, 4-deep
// unroll -> 4 gathers in flight per wave), LDS reduction across waves.
// Rationale: previous version (1 wave/row, 2-deep) ran accum at ~1.9 TB/s
// effective on an L3-resident table => latency-bound, not bytes-bound.

struct Pair { int c; float v; };

// ---- Fused: weight f32->f16 conversion (grid-stride, 8 floats/thread) + row histogram ----
__global__ void convert_count_kernel(const float* __restrict__ weight,
                                     __half* __restrict__ wf16, long long ngroups,
                                     const int* __restrict__ rows,
                                     int* __restrict__ counts, int nnz) {
    long long i = (long long)blockIdx.x * blockDim.x + threadIdx.x;
    if (i < nnz) atomicAdd(&counts[rows[(int)i]], 1);
    const float4* w4 = (const float4*)weight;
    float4* dst = (float4*)wf16;               // 16B = 8 halfs per group
    long long stride = (long long)gridDim.x * blockDim.x;
    for (long long g = i; g < ngroups; g += stride) {
        float4 a = w4[2 * g];
        float4 b = w4[2 * g + 1];
        union { __half2 h2[4]; float4 f4; } u;
        u.h2[0] = __floats2half2_rn(a.x, a.y);
        u.h2[1] = __floats2half2_rn(a.z, a.w);
        u.h2[2] = __floats2half2_rn(b.x, b.y);
        u.h2[3] = __floats2half2_rn(b.z, b.w);
        dst[g] = u.f4;
    }
}

// ---- Exclusive scan over 4096 counts (1 block); writes offsets AND cursor ----
__global__ void scan_kernel(const int* __restrict__ counts, int* __restrict__ offsets,
                            int* __restrict__ cursor, int n_rows) {
    __shared__ int partial[256];
    const int t = threadIdx.x;
    const int per = (n_rows + 255) / 256;
    const int base = t * per;
    int sum = 0;
    for (int j = 0; j < per; ++j) {
        int idx = base + j;
        if (idx < n_rows) sum += counts[idx];
    }
    partial[t] = sum;
    __syncthreads();
    for (int off = 1; off < 256; off <<= 1) {
        int v = 0;
        if (t >= off) v = partial[t - off];
        __syncthreads();
        if (t >= off) partial[t] += v;
        __syncthreads();
    }
    int run = (t == 0) ? 0 : partial[t - 1];
    for (int j = 0; j < per; ++j) {
        int idx = base + j;
        if (idx < n_rows) {
            offsets[idx] = run;
            cursor[idx] = run;
            run += counts[idx];
        }
    }
    if (t == 255) offsets[n_rows] = run;
}

// ---- Scatter nnz into row-sorted (col,val) pairs ----
__global__ void scatter_pairs_kernel(const int* __restrict__ rows, const int* __restrict__ cols,
                                     const float* __restrict__ values, int* __restrict__ cursor,
                                     int2* __restrict__ pairs, int nnz) {
    int i = blockIdx.x * blockDim.x + threadIdx.x;
    if (i < nnz) {
        int p = atomicAdd(&cursor[rows[i]], 1);
        pairs[p] = make_int2(cols[i], __float_as_int(values[i]));
    }
}

// ---- Accumulate: 4 waves per output row; wave covers all 512 cols (lane = 8 fp16) ----
// Each wave takes a contiguous quarter of the row's nnz with 4-deep unroll
// (4 independent 16B/lane gathers in flight), then LDS cross-wave reduce.
__global__ __launch_bounds__(256) void accum_f16_kernel(
    const __half* __restrict__ wf16, const float* __restrict__ bias,
    const int* __restrict__ offsets, const int2* __restrict__ pairs,
    float* __restrict__ out, int out_f) {
    const int wave = threadIdx.x >> 6;
    const int lane = threadIdx.x & 63;
    const int row = blockIdx.x;
    const int start = offsets[row];
    const int end = offsets[row + 1];
    const int len = end - start;
    const int per = (len + 3) >> 2;           // nnz per wave
    int p = start + wave * per;
    int pe = p + per;
    if (pe > end) pe = end;
    if (p > end) p = end;

    const float4* wbase = (const float4*)wf16;   // one float4 = 8 halfs
    float acc[8] = {0.f, 0.f, 0.f, 0.f, 0.f, 0.f, 0.f, 0.f};

    for (; p + 4 <= pe; p += 4) {
        int2 e0 = pairs[p];
        int2 e1 = pairs[p + 1];
        int2 e2 = pairs[p + 2];
        int2 e3 = pairs[p + 3];
        float4 w0 = wbase[(long long)e0.x * 64 + lane];
        float4 w1 = wbase[(long long)e1.x * 64 + lane];
        float4 w2 = wbase[(long long)e2.x * 64 + lane];
        float4 w3 = wbase[(long long)e3.x * 64 + lane];
        float v0 = __int_as_float(e0.y);
        float v1 = __int_as_float(e1.y);
        float v2 = __int_as_float(e2.y);
        float v3 = __int_as_float(e3.y);
        const __half2* h0 = (const __half2*)&w0;
        const __half2* h1 = (const __half2*)&w1;
        const __half2* h2 = (const __half2*)&w2;
        const __half2* h3 = (const __half2*)&w3;
#pragma unroll
        for (int j = 0; j < 4; ++j) {
            float2 f0 = __half22float2(h0[j]);
            float2 f1 = __half22float2(h1[j]);
            float2 f2 = __half22float2(h2[j]);
            float2 f3 = __half22float2(h3[j]);
            acc[2 * j]     += v0 * f0.x + v1 * f1.x + v2 * f2.x + v3 * f3.x;
            acc[2 * j + 1] += v0 * f0.y + v1 * f1.y + v2 * f2.y + v3 * f3.y;
        }
    }
    for (; p < pe; ++p) {
        int2 e0 = pairs[p];
        float v0 = __int_as_float(e0.y);
        float4 w0 = wbase[(long long)e0.x * 64 + lane];
        const __half2* h0 = (const __half2*)&w0;
#pragma unroll
        for (int j = 0; j < 4; ++j) {
            float2 f0 = __half22float2(h0[j]);
            acc[2 * j]     += v0 * f0.x;
            acc[2 * j + 1] += v0 * f0.y;
        }
    }

    // Cross-wave reduce: 4 x 512 f32 partials in LDS (8 KB), then 256 threads
    // each finish 2 columns. Cost is ~1 LDS round-trip per block — negligible
    // vs ~132 KB of global gather traffic per block.
    __shared__ float red[4][512];
    {
        float4* dst = (float4*)&red[wave][lane * 8];
        dst[0] = make_float4(acc[0], acc[1], acc[2], acc[3]);
        dst[1] = make_float4(acc[4], acc[5], acc[6], acc[7]);
    }
    __syncthreads();
    const int c = threadIdx.x * 2;
    float s0 = red[0][c] + red[1][c] + red[2][c] + red[3][c];
    float s1 = red[0][c + 1] + red[1][c + 1] + red[2][c + 1] + red[3][c + 1];
    float2 b = *(const float2*)(bias + c);
    *(float2*)(out + (long long)row * out_f + c) = make_float2(s0 + b.x, s1 + b.y);
}

// ================= Fallback path (ws too small / shape mismatch): f32 scheme =================
__global__ void count_rows_kernel(const int* __restrict__ rows, int* __restrict__ counts, int nnz) {
    int i = blockIdx.x * blockDim.x + threadIdx.x;
    if (i < nnz) atomicAdd(&counts[rows[i]], 1);
}
__global__ void scatter_kernel(const int* __restrict__ rows, int* __restrict__ cursor,
                               int* __restrict__ perm, int nnz) {
    int i = blockIdx.x * blockDim.x + threadIdx.x;
    if (i < nnz) {
        int p = atomicAdd(&cursor[rows[i]], 1);
        perm[p] = i;
    }
}
__global__ void accum_kernel(const float* __restrict__ values, const float* __restrict__ weight,
                             const float* __restrict__ bias, const int* __restrict__ cols,
                             const int* __restrict__ offsets, const int* __restrict__ perm,
                             float* __restrict__ out, int out_f) {
    const int r = blockIdx.x;
    const int start = offsets[r];
    const int end = offsets[r + 1];
    const int step = blockDim.x * 4;
    for (int base = threadIdx.x * 4; base < out_f; base += step) {
        float4 acc = make_float4(0.f, 0.f, 0.f, 0.f);
        for (int p = start; p < end; ++p) {
            int k = perm[p];
            float v = values[k];
            long long c = cols[k];
            float4 w = *(const float4*)(weight + c * (long long)out_f + base);
            acc.x += v * w.x; acc.y += v * w.y; acc.z += v * w.z; acc.w += v * w.w;
        }
        float4 b = *(const float4*)(bias + base);
        acc.x += b.x; acc.y += b.y; acc.z += b.z; acc.w += b.w;
        *(float4*)(out + (long long)r * out_f + base) = acc;
    }
}

static size_t align_up(size_t x, size_t a) { return (x + a - 1) & ~(a - 1); }

extern "C" void kernel_launch(void* const* d_in, const int* in_sizes, int n_in,
                              void* d_out, int out_size, void* d_ws, size_t ws_size,
                              hipStream_t stream) {
    const float* values = (const float*)d_in[0];
    const float* weight = (const float*)d_in[1];
    const float* bias   = (const float*)d_in[2];
    const int*   rows   = (const int*)d_in[3];
    const int*   cols   = (const int*)d_in[4];

    const int nnz = in_sizes[0];
    const long long wtotal = in_sizes[1];
    const int out_f = in_sizes[2];
    const int n_rows = out_size / out_f;
    float* out = (float*)d_out;

    // ws layout: wf16[wtotal] | counts[n_rows] | offsets[n_rows+1] | cursor[n_rows] | pairs[nnz]
    size_t off_wf16 = 0;
    size_t off_counts = align_up(off_wf16 + (size_t)wtotal * sizeof(__half), 256);
    size_t off_offsets = off_counts + (size_t)n_rows * sizeof(int);
    size_t off_cursor = off_offsets + (size_t)(n_rows + 1) * sizeof(int);
    size_t off_pairs = align_up(off_cursor + (size_t)n_rows * sizeof(int), 256);
    size_t need = off_pairs + (size_t)nnz * sizeof(int2);

    if (ws_size >= need && out_f == 512) {
        char* ws = (char*)d_ws;
        __half* wf16 = (__half*)(ws + off_wf16);
        int* counts = (int*)(ws + off_counts);
        int* offsets = (int*)(ws + off_offsets);
        int* cursor = (int*)(ws + off_cursor);
        int2* pairs = (int2*)(ws + off_pairs);

        hipMemsetAsync(counts, 0, (size_t)n_rows * sizeof(int), stream);

        long long ngroups = wtotal / 8;
        int cc_blocks = (int)((ngroups + 255) / 256);
        convert_count_kernel<<<cc_blocks, 256, 0, stream>>>(weight, wf16, ngroups,
                                                            rows, counts, nnz);
        scan_kernel<<<1, 256, 0, stream>>>(counts, offsets, cursor, n_rows);
        int sc_blocks = (nnz + 255) / 256;
        scatter_pairs_kernel<<<sc_blocks, 256, 0, stream>>>(rows, cols, values, cursor,
                                                            pairs, nnz);
        accum_f16_kernel<<<n_rows, 256, 0, stream>>>(wf16, bias, offsets, pairs,
                                                     out, out_f);
    } else {
        // f32 fallback: counts | offsets | cursor | perm
        int* counts = (int*)d_ws;
        int* offsets = counts + n_rows;
        int* cursor = offsets + n_rows + 1;
        int* perm = cursor + n_rows;
        hipMemsetAsync(counts, 0, (size_t)n_rows * sizeof(int), stream);
        int blocks = (nnz + 255) / 256;
        count_rows_kernel<<<blocks, 256, 0, stream>>>(rows, counts, nnz);
        scan_kernel<<<1, 256, 0, stream>>>(counts, offsets, cursor, n_rows);
        scatter_kernel<<<blocks, 256, 0, stream>>>(rows, cursor, perm, nnz);
        accum_kernel<<<n_rows, 128, 0, stream>>>(values, weight, bias, cols,
                                                 offsets, perm, out, out_f);
    }
}